// Round 1
// baseline (258.125 us; speedup 1.0000x reference)
//
#include <hip/hip_runtime.h>
#include <hip/hip_bf16.h>

// loss = -sum_i( logp[i, target[i]] * reward[i] ),  i in [0, N), N = 32*179 = 5728
// logp is (N, V) fp32 row-major, V = 9487.
//
// Single block, 1024 threads (16 waves). Each thread grid-strides over rows,
// gathers one float per row, accumulates locally; then butterfly shuffle
// reduction within each 64-lane wave, per-wave partials to LDS, lane 0 of
// wave 0 sums 16 partials and writes -sum. Deterministic, no atomics, no
// need to pre-zero d_out.
__global__ __launch_bounds__(1024) void
RewardCriterion2_kernel(const float* __restrict__ logp,
                        const float* __restrict__ reward,
                        const int* __restrict__ target,
                        float* __restrict__ out,
                        int N, int V) {
    float acc = 0.0f;
    for (int i = threadIdx.x; i < N; i += 1024) {
        long long idx = (long long)i * (long long)V + (long long)target[i];
        acc += logp[idx] * reward[i];
    }

    // wave (64-lane) reduction
    #pragma unroll
    for (int off = 32; off > 0; off >>= 1) {
        acc += __shfl_down(acc, off, 64);
    }

    __shared__ float warp_sums[16];
    const int lane = threadIdx.x & 63;
    const int wave = threadIdx.x >> 6;
    if (lane == 0) warp_sums[wave] = acc;
    __syncthreads();

    if (threadIdx.x == 0) {
        float total = 0.0f;
        #pragma unroll
        for (int w = 0; w < 16; ++w) total += warp_sums[w];
        out[0] = -total;
    }
}

extern "C" void kernel_launch(void* const* d_in, const int* in_sizes, int n_in,
                              void* d_out, int out_size, void* d_ws, size_t ws_size,
                              hipStream_t stream) {
    const float* logp   = (const float*)d_in[0];  // (N, V) fp32
    const float* reward = (const float*)d_in[1];  // (N,) fp32
    // d_in[2] is batchsize_cap scalar (unused; N derived from reward size)
    const int*   target = (const int*)d_in[3];    // (N,) int32

    float* out = (float*)d_out;

    const int N = in_sizes[1];
    const int V = in_sizes[0] / N;  // 9487

    RewardCriterion2_kernel<<<1, 1024, 0, stream>>>(logp, reward, target, out, N, V);
}

// Round 2
// 246.449 us; speedup vs baseline: 1.0474x; 1.0474x over previous
//
#include <hip/hip_runtime.h>
#include <hip/hip_bf16.h>

// loss = -sum_i( logp[i, target[i]] * reward[i] ),  i in [0, N), N = 32*179 = 5728
// logp is (N, V) fp32 row-major, V = 9487.
//
// Two-kernel deterministic reduction:
//  k1: 23 blocks x 256 threads, one row per thread -> per-block partial in d_ws
//      (every slot written, so 0xAA workspace poison is harmless)
//  k2: one wave reduces the 23 partials, writes -sum.
// Maximizes memory-level parallelism: all 5728 scattered gathers issue at once
// across 23 CUs instead of 6 serial dependent rounds on 1 CU.

__global__ __launch_bounds__(256) void
gather_partial(const float* __restrict__ logp,
               const float* __restrict__ reward,
               const int* __restrict__ target,
               float* __restrict__ partial,
               int N, int V) {
    const int i = blockIdx.x * 256 + threadIdx.x;
    float v = 0.0f;
    if (i < N) {
        const long long idx = (long long)i * (long long)V + (long long)target[i];
        v = logp[idx] * reward[i];
    }

    // 64-lane wave reduction
    #pragma unroll
    for (int off = 32; off > 0; off >>= 1) {
        v += __shfl_down(v, off, 64);
    }

    __shared__ float wsum[4];
    const int lane = threadIdx.x & 63;
    const int wave = threadIdx.x >> 6;
    if (lane == 0) wsum[wave] = v;
    __syncthreads();

    if (threadIdx.x == 0) {
        partial[blockIdx.x] = wsum[0] + wsum[1] + wsum[2] + wsum[3];
    }
}

__global__ __launch_bounds__(64) void
finalize(const float* __restrict__ partial, float* __restrict__ out, int nb) {
    float v = (threadIdx.x < (unsigned)nb) ? partial[threadIdx.x] : 0.0f;
    #pragma unroll
    for (int off = 32; off > 0; off >>= 1) {
        v += __shfl_down(v, off, 64);
    }
    if (threadIdx.x == 0) out[0] = -v;
}

extern "C" void kernel_launch(void* const* d_in, const int* in_sizes, int n_in,
                              void* d_out, int out_size, void* d_ws, size_t ws_size,
                              hipStream_t stream) {
    const float* logp   = (const float*)d_in[0];  // (N, V) fp32
    const float* reward = (const float*)d_in[1];  // (N,) fp32
    // d_in[2] is batchsize_cap scalar (unused; N derived from reward size)
    const int*   target = (const int*)d_in[3];    // (N,) int32

    float* out = (float*)d_out;
    float* partial = (float*)d_ws;

    const int N = in_sizes[1];
    const int V = in_sizes[0] / N;  // 9487
    const int nb = (N + 255) / 256; // 23

    gather_partial<<<nb, 256, 0, stream>>>(logp, reward, target, partial, N, V);
    finalize<<<1, 64, 0, stream>>>(partial, out, nb);
}